// Round 8
// baseline (388.094 us; speedup 1.0000x reference)
//
#include <hip/hip_runtime.h>

// ChamferLoss: preds (8,3,2048,8) f32, gts (8,3,2048) f32, idx (64,2) int.
// x[b][n][c] = preds[i0, c, n, m1]; y[b][n][c] = gts[i0, c, n]; i0=idx[b,0], m1=idx[b,1].
// P[i][j] = rx_i + ry_j - 2 x_i.y_j ; loss = (sum_j min_i P + sum_i min_j P)/64.
// R8: feed the distance loop from PACKED global float4 arrays (VMEM/L2 pipe)
// instead of LDS — R7 analysis showed the DS pipe (b128 reads + swizzles) was
// the co-bottleneck (~850 CU-cyc/blk/jt vs 640 VALU). LDS now only 2KB scolw.

#define NPTS 2048
#define NB 64
#define BLK 256
#define NMIN (2 * NB * NPTS)    // 131072 row slots + 131072 col slots

#define PREDS_A 49152           // 3*2048*8
#define PREDS_C 16384           // 2048*8
#define GTS_A 6144              // 3*2048
#define GTS_C 2048

// ---- main-path geometry: thread tile Q=16 x R=8 ----
#define IT 256                  // rows per block
#define NIT (NPTS / IT)         // 8
#define JT 128                  // cols per jt step
#define NJT (NPTS / JT)         // 16

// ws layout
#define OFF_PARTIAL (NMIN * 4)                    // 1 KiB floats
#define OFF_QPACK   (OFF_PARTIAL + 4096)
#define OFF_YPACK   (OFF_QPACK + NB * NPTS * 16)
#define WS_REQ      (OFF_YPACK + NB * NPTS * 16)  // ~5.25 MB

static __device__ __forceinline__ float min3f(float a, float b, float c) {
    return fminf(fminf(a, b), c);
}

// ---------- fused init + pack: grid 1536 ----------
__global__ __launch_bounds__(256) void cf_initpack(
    const float* __restrict__ preds, const float* __restrict__ gts,
    const int* __restrict__ idx, unsigned* __restrict__ colbuf,
    float4* __restrict__ qpack, float4* __restrict__ ypack)
{
    const int blk = blockIdx.x;
    const int tid = threadIdx.x;
    if (blk < 512) {                      // colbuf = +inf
        colbuf[blk * 256 + tid] = 0x7F800000u;
    } else if (blk < 1024) {              // qpack[b][i] = (-2x, rx)
        const int p = (blk - 512) * 256 + tid;
        const int b = p >> 11, i = p & 2047;
        const int i0 = idx[2 * b], m1 = idx[2 * b + 1];
        const float* pb = preds + i0 * PREDS_A + m1 + i * 8;
        const float q0 = pb[0], q1 = pb[PREDS_C], q2 = pb[2 * PREDS_C];
        const float rq = fmaf(q0, q0, fmaf(q1, q1, q2 * q2));
        qpack[p] = make_float4(-2.f * q0, -2.f * q1, -2.f * q2, rq);
    } else {                              // ypack[b][j] = (y, ry)
        const int p = (blk - 1024) * 256 + tid;
        const int b = p >> 11, j = p & 2047;
        const int i0 = idx[2 * b];
        const float* gb = gts + i0 * GTS_A + j;
        const float r0 = gb[0], r1 = gb[GTS_C], r2 = gb[2 * GTS_C];
        const float rr = fmaf(r0, r0, fmaf(r1, r1, r2 * r2));
        ypack[p] = make_float4(r0, r1, r2, rr);
    }
}

// ---------- main: Q16 x R8 register tile, VMEM-fed, LDS only for col flush ----------
__global__ __launch_bounds__(BLK, 3) void cf_tile2(
    const float4* __restrict__ qpack, const float4* __restrict__ ypack,
    unsigned* __restrict__ minbuf)
{
    const int tid = threadIdx.x;
    const int ty = tid >> 4, tx = tid & 15;
    const int bid = blockIdx.x;       // b*8 + it
    const int it = bid & 7;
    const int b = bid >> 3;

    __shared__ float scolw[4][JT];    // per-wave col partials (2 KB total LDS)

    // ---- 16 queries in registers ----
    const float4* qb = qpack + b * NPTS + it * IT + ty * 16;
    float nq0[16], nq1[16], nq2[16], rq[16], rmin[16];
#pragma unroll
    for (int u = 0; u < 16; ++u) {
        const float4 q = qb[u];
        nq0[u] = q.x; nq1[u] = q.y; nq2[u] = q.z; rq[u] = q.w;
        rmin[u] = INFINITY;
    }

    unsigned* rowbuf = minbuf;
    unsigned* colbuf = minbuf + NB * NPTS;
    const float4* yb = ypack + b * NPTS;

    for (int jt = 0; jt < NJT; ++jt) {
        const float4* rp = yb + jt * JT + tx * 8;
        float4 r[8];
#pragma unroll
        for (int v = 0; v < 8; ++v) r[v] = rp[v];

        float cmin[8];
#pragma unroll
        for (int v = 0; v < 8; ++v) cmin[v] = INFINITY;

        // ---- 16x8 register tile as 2x2 micro-tiles ----
#pragma unroll
        for (int v = 0; v < 8; v += 2) {
#pragma unroll
            for (int u = 0; u < 16; u += 2) {
                float s00 = fmaf(nq2[u], r[v].z, r[v].w);
                s00 = fmaf(nq1[u], r[v].y, s00);
                s00 = fmaf(nq0[u], r[v].x, s00);
                float s01 = fmaf(nq2[u], r[v + 1].z, r[v + 1].w);
                s01 = fmaf(nq1[u], r[v + 1].y, s01);
                s01 = fmaf(nq0[u], r[v + 1].x, s01);
                float s10 = fmaf(nq2[u + 1], r[v].z, r[v].w);
                s10 = fmaf(nq1[u + 1], r[v].y, s10);
                s10 = fmaf(nq0[u + 1], r[v].x, s10);
                float s11 = fmaf(nq2[u + 1], r[v + 1].z, r[v + 1].w);
                s11 = fmaf(nq1[u + 1], r[v + 1].y, s11);
                s11 = fmaf(nq0[u + 1], r[v + 1].x, s11);
                rmin[u]     = min3f(s00, s01, rmin[u]);      // rq added at flush
                rmin[u + 1] = min3f(s10, s11, rmin[u + 1]);
                const float d00 = s00 + rq[u];
                const float d10 = s10 + rq[u + 1];
                const float d01 = s01 + rq[u];
                const float d11 = s11 + rq[u + 1];
                cmin[v]     = min3f(d00, d10, cmin[v]);
                cmin[v + 1] = min3f(d01, d11, cmin[v + 1]);
            }
        }

        // ---- col reduce: 16 ty = 4 in-wave (xor 16,32) + 4 cross-wave via LDS ----
#pragma unroll
        for (int v = 0; v < 8; ++v) {
            float c = cmin[v];
            c = fminf(c, __shfl_xor(c, 16, 64));
            c = fminf(c, __shfl_xor(c, 32, 64));
            cmin[v] = c;
        }
        if (((tid >> 4) & 3) == 0) {             // one ty per wave
            const int w = tid >> 6;
            *(float4*)&scolw[w][tx * 8]     = make_float4(cmin[0], cmin[1], cmin[2], cmin[3]);
            *(float4*)&scolw[w][tx * 8 + 4] = make_float4(cmin[4], cmin[5], cmin[6], cmin[7]);
        }
        __syncthreads();
        if (tid < JT) {
            float m = fminf(min3f(scolw[0][tid], scolw[1][tid], scolw[2][tid]), scolw[3][tid]);
            m = fmaxf(m, 0.0f);
            atomicMin(&colbuf[b * NPTS + jt * JT + tid], __float_as_uint(m));
        }
        __syncthreads();
    }

    // ---- row flush: reduce over 16 tx, exclusive store ----
#pragma unroll
    for (int u = 0; u < 16; ++u) {
        float rm = rmin[u];
        rm = fminf(rm, __shfl_xor(rm, 1, 16));
        rm = fminf(rm, __shfl_xor(rm, 2, 16));
        rm = fminf(rm, __shfl_xor(rm, 4, 16));
        rm = fminf(rm, __shfl_xor(rm, 8, 16));
        rmin[u] = rm;
    }
    if (tx == 0) {
#pragma unroll
        for (int u = 0; u < 16; ++u) {
            const float d = fmaxf(rmin[u] + rq[u], 0.0f);
            rowbuf[b * NPTS + it * IT + ty * 16 + u] = __float_as_uint(d);
        }
    }
}

// ================= fallback path (R6, LDS-staged) if ws too small =================
#define FIT 128
#define FJT 128
#define PADI(j) ((j) + ((j) >> 4))

__global__ __launch_bounds__(256) void cf_init(unsigned* __restrict__ colbuf) {
    int i = blockIdx.x * 256 + threadIdx.x;
    colbuf[i] = 0x7F800000u;
}

__global__ __launch_bounds__(BLK, 4) void cf_tile_lds(
    const float* __restrict__ preds, const float* __restrict__ gts,
    const int* __restrict__ idx, unsigned* __restrict__ minbuf)
{
    const int tid = threadIdx.x;
    const int bid = blockIdx.x;
    const int it = bid & 15;
    const int b = bid >> 4;
    const int i0 = idx[2 * b];
    const int m1 = idx[2 * b + 1];
    const float* pbase = preds + i0 * PREDS_A + m1;
    const float* gbase = gts + i0 * GTS_A;

    __shared__ float4 sq[PADI(FIT - 1) + 2];
    __shared__ float4 sr[PADI(NPTS - 1) + 2];
    __shared__ float  scolw[4][FJT];

    if (tid < FIT) {
        const int i = it * FIT + tid;
        const float q0 = pbase[i * 8];
        const float q1 = pbase[i * 8 + PREDS_C];
        const float q2 = pbase[i * 8 + 2 * PREDS_C];
        const float rq = fmaf(q0, q0, fmaf(q1, q1, q2 * q2));
        sq[PADI(tid)] = make_float4(-2.f * q0, -2.f * q1, -2.f * q2, rq);
    }
#pragma unroll
    for (int k = 0; k < 8; ++k) {
        const int j = tid + BLK * k;
        const float r0 = gbase[j];
        const float r1 = gbase[j + GTS_C];
        const float r2 = gbase[j + 2 * GTS_C];
        const float rr = fmaf(r0, r0, fmaf(r1, r1, r2 * r2));
        sr[PADI(j)] = make_float4(r0, r1, r2, rr);
    }
    __syncthreads();

    const int ty = tid >> 4, tx = tid & 15;
    float nq0[8], nq1[8], nq2[8], rq[8], rmin[8];
#pragma unroll
    for (int u = 0; u < 8; ++u) {
        const float4 q = sq[PADI(ty * 8 + u)];
        nq0[u] = q.x; nq1[u] = q.y; nq2[u] = q.z; rq[u] = q.w;
        rmin[u] = INFINITY;
    }
    unsigned* rowbuf = minbuf;
    unsigned* colbuf = minbuf + NB * NPTS;

    for (int jt = 0; jt < NPTS / FJT; ++jt) {
        float4 r[8];
        const int rb = PADI(jt * FJT + tx * 8);
#pragma unroll
        for (int v = 0; v < 8; ++v) r[v] = sr[rb + v];
        float cmin[8];
#pragma unroll
        for (int v = 0; v < 8; ++v) cmin[v] = INFINITY;
#pragma unroll
        for (int v = 0; v < 8; v += 2) {
#pragma unroll
            for (int u = 0; u < 8; u += 2) {
                float s00 = fmaf(nq2[u], r[v].z, r[v].w);
                s00 = fmaf(nq1[u], r[v].y, s00);
                s00 = fmaf(nq0[u], r[v].x, s00);
                float s01 = fmaf(nq2[u], r[v + 1].z, r[v + 1].w);
                s01 = fmaf(nq1[u], r[v + 1].y, s01);
                s01 = fmaf(nq0[u], r[v + 1].x, s01);
                float s10 = fmaf(nq2[u + 1], r[v].z, r[v].w);
                s10 = fmaf(nq1[u + 1], r[v].y, s10);
                s10 = fmaf(nq0[u + 1], r[v].x, s10);
                float s11 = fmaf(nq2[u + 1], r[v + 1].z, r[v + 1].w);
                s11 = fmaf(nq1[u + 1], r[v + 1].y, s11);
                s11 = fmaf(nq0[u + 1], r[v + 1].x, s11);
                rmin[u]     = min3f(s00, s01, rmin[u]);
                rmin[u + 1] = min3f(s10, s11, rmin[u + 1]);
                const float d00 = s00 + rq[u];
                const float d10 = s10 + rq[u + 1];
                const float d01 = s01 + rq[u];
                const float d11 = s11 + rq[u + 1];
                cmin[v]     = min3f(d00, d10, cmin[v]);
                cmin[v + 1] = min3f(d01, d11, cmin[v + 1]);
            }
        }
#pragma unroll
        for (int v = 0; v < 8; ++v) {
            float c = cmin[v];
            c = fminf(c, __shfl_xor(c, 16, 64));
            c = fminf(c, __shfl_xor(c, 32, 64));
            cmin[v] = c;
        }
        if (((tid >> 4) & 3) == 0) {
            const int w = tid >> 6;
            *(float4*)&scolw[w][tx * 8]     = make_float4(cmin[0], cmin[1], cmin[2], cmin[3]);
            *(float4*)&scolw[w][tx * 8 + 4] = make_float4(cmin[4], cmin[5], cmin[6], cmin[7]);
        }
        __syncthreads();
        if (tid < FJT) {
            float m = fminf(min3f(scolw[0][tid], scolw[1][tid], scolw[2][tid]), scolw[3][tid]);
            m = fmaxf(m, 0.0f);
            atomicMin(&colbuf[b * NPTS + jt * FJT + tid], __float_as_uint(m));
        }
        __syncthreads();
    }
#pragma unroll
    for (int u = 0; u < 8; ++u) {
        float rm = rmin[u];
        rm = fminf(rm, __shfl_xor(rm, 1, 16));
        rm = fminf(rm, __shfl_xor(rm, 2, 16));
        rm = fminf(rm, __shfl_xor(rm, 4, 16));
        rm = fminf(rm, __shfl_xor(rm, 8, 16));
        rmin[u] = rm;
    }
    if (tx == 0) {
#pragma unroll
        for (int u = 0; u < 8; ++u) {
            const float d = fmaxf(rmin[u] + rq[u], 0.0f);
            rowbuf[b * NPTS + it * FIT + ty * 8 + u] = __float_as_uint(d);
        }
    }
}

// ================= final reductions =================
__global__ __launch_bounds__(256) void cf_reduce1(const unsigned* __restrict__ minbuf,
                                                  float* __restrict__ partial) {
    __shared__ float sm[4];
    const int base = blockIdx.x * 1024;
    float s = 0.0f;
    for (int k = threadIdx.x; k < 1024; k += 256)
        s += __uint_as_float(minbuf[base + k]);
#pragma unroll
    for (int off = 32; off > 0; off >>= 1)
        s += __shfl_down(s, off, 64);
    if ((threadIdx.x & 63) == 0) sm[threadIdx.x >> 6] = s;
    __syncthreads();
    if (threadIdx.x == 0)
        partial[blockIdx.x] = sm[0] + sm[1] + sm[2] + sm[3];
}

__global__ __launch_bounds__(256) void cf_reduce2(const float* __restrict__ partial,
                                                  float* __restrict__ out) {
    __shared__ float sm[4];
    float s = partial[threadIdx.x];
#pragma unroll
    for (int off = 32; off > 0; off >>= 1)
        s += __shfl_down(s, off, 64);
    if ((threadIdx.x & 63) == 0) sm[threadIdx.x >> 6] = s;
    __syncthreads();
    if (threadIdx.x == 0)
        out[0] = (sm[0] + sm[1] + sm[2] + sm[3]) * (1.0f / 64.0f);
}

extern "C" void kernel_launch(void* const* d_in, const int* in_sizes, int n_in,
                              void* d_out, int out_size, void* d_ws, size_t ws_size,
                              hipStream_t stream) {
    const float* preds = (const float*)d_in[0];
    const float* gts   = (const float*)d_in[1];
    const int*   idx   = (const int*)d_in[2];
    float* out = (float*)d_out;

    unsigned* minbuf = (unsigned*)d_ws;
    unsigned* colbuf = minbuf + NB * NPTS;
    float* partial   = (float*)((char*)d_ws + OFF_PARTIAL);

    if (ws_size >= (size_t)WS_REQ) {
        float4* qpack = (float4*)((char*)d_ws + OFF_QPACK);
        float4* ypack = (float4*)((char*)d_ws + OFF_YPACK);
        cf_initpack<<<1536, 256, 0, stream>>>(preds, gts, idx, colbuf, qpack, ypack);
        cf_tile2<<<NB * NIT, BLK, 0, stream>>>(qpack, ypack, minbuf);
    } else {
        cf_init<<<(NB * NPTS) / 256, 256, 0, stream>>>(colbuf);
        cf_tile_lds<<<NB * (NPTS / FIT), BLK, 0, stream>>>(preds, gts, idx, minbuf);
    }
    cf_reduce1<<<NMIN / 1024, 256, 0, stream>>>(minbuf, partial);
    cf_reduce2<<<1, 256, 0, stream>>>(partial, out);
}

// Round 9
// 55.871 us; speedup vs baseline: 6.9462x; 6.9462x over previous
//
#include <hip/hip_runtime.h>

// ChamferLoss via MFMA: preds (8,3,2048,8) f32, gts (8,3,2048) f32, idx (64,2) int.
// P[i][j] = rx_i + ry_j - 2 x_i.y_j computed ENTIRELY inside one
// mfma_f32_16x16x32_bf16 per 16x16 tile via split-bf16 K-packing:
//   A_k = [ah0..2, ah0..2, al0..2, rxh, rxl, 1, 1, 0] (a = -2x, split hi/lo)
//   B_k = [yh0..2, yl0..2, yh0..2, 1, 1, ryh, ryl, 0]
//   sum = (-2)(xh.yh + xh.yl + xl.yh) + rx + ry  (error ~2^-18 rel)
// Epilogue is pure min work (~1.3 VALU op/elem) -> MFMA pipe carries the FLOPs.

#define NPTS 2048
#define NB 64
#define BLK 256
#define NMIN (2 * NB * NPTS)

#define PREDS_A 49152
#define PREDS_C 16384
#define GTS_A 6144
#define GTS_C 2048

#define SROW 40                 // padded LDS row: 16 data + 16 zero + 8 pad (80 B)

// ws layout
#define OFF_PARTIAL (NMIN * 4)                       // floats for reduce1
#define OFF_QPK     (OFF_PARTIAL + 4096)             // 64*2048*16 ushort = 4 MB
#define OFF_YPK     (OFF_QPK + NB * NPTS * 32)
#define WS_REQ      (OFF_YPK + NB * NPTS * 32)       // ~9.4 MB

using bf16x8  = __attribute__((ext_vector_type(8))) __bf16;
using short8v = __attribute__((ext_vector_type(8))) short;
using f32x4   = __attribute__((ext_vector_type(4))) float;

static __device__ __forceinline__ unsigned short f2bf(float f) {
    unsigned u = __float_as_uint(f);
    u = u + 0x7FFFu + ((u >> 16) & 1u);      // RNE
    return (unsigned short)(u >> 16);
}
static __device__ __forceinline__ float bf2f(unsigned short h) {
    return __uint_as_float(((unsigned)h) << 16);
}
static __device__ __forceinline__ float min3f(float a, float b, float c) {
    return fminf(fminf(a, b), c);
}

// ---------- pack + init: 1536 blocks ----------
__global__ __launch_bounds__(256) void cf_pack(
    const float* __restrict__ preds, const float* __restrict__ gts,
    const int* __restrict__ idx, unsigned* __restrict__ colbuf,
    unsigned short* __restrict__ qpk, unsigned short* __restrict__ ypk)
{
    const int blk = blockIdx.x, tid = threadIdx.x;
    const unsigned short one = 0x3F80;
    if (blk < 512) {
        colbuf[blk * 256 + tid] = 0x7F800000u;
    } else if (blk < 1024) {
        const int p = (blk - 512) * 256 + tid;
        const int b = p >> 11, i = p & 2047;
        const int i0 = idx[2 * b], m1 = idx[2 * b + 1];
        const float* pb = preds + i0 * PREDS_A + m1 + i * 8;
        const float x0 = pb[0], x1 = pb[PREDS_C], x2 = pb[2 * PREDS_C];
        const float rx = fmaf(x0, x0, fmaf(x1, x1, x2 * x2));
        const float a0 = -2.f * x0, a1 = -2.f * x1, a2 = -2.f * x2;
        const unsigned short h0 = f2bf(a0), h1 = f2bf(a1), h2 = f2bf(a2);
        const unsigned short l0 = f2bf(a0 - bf2f(h0));
        const unsigned short l1 = f2bf(a1 - bf2f(h1));
        const unsigned short l2 = f2bf(a2 - bf2f(h2));
        const unsigned short rh = f2bf(rx), rl = f2bf(rx - bf2f(rh));
        alignas(16) unsigned short t[16] =
            {h0, h1, h2, h0, h1, h2, l0, l1, l2, rh, rl, one, one, 0, 0, 0};
        uint4* dst = (uint4*)(qpk + (size_t)p * 16);
        dst[0] = *(const uint4*)&t[0];
        dst[1] = *(const uint4*)&t[8];
    } else {
        const int p = (blk - 1024) * 256 + tid;
        const int b = p >> 11, j = p & 2047;
        const int i0 = idx[2 * b];
        const float* gb = gts + i0 * GTS_A + j;
        const float y0 = gb[0], y1 = gb[GTS_C], y2 = gb[2 * GTS_C];
        const float ry = fmaf(y0, y0, fmaf(y1, y1, y2 * y2));
        const unsigned short h0 = f2bf(y0), h1 = f2bf(y1), h2 = f2bf(y2);
        const unsigned short l0 = f2bf(y0 - bf2f(h0));
        const unsigned short l1 = f2bf(y1 - bf2f(h1));
        const unsigned short l2 = f2bf(y2 - bf2f(h2));
        const unsigned short rh = f2bf(ry), rl = f2bf(ry - bf2f(rh));
        alignas(16) unsigned short t[16] =
            {h0, h1, h2, l0, l1, l2, h0, h1, h2, one, one, rh, rl, 0, 0, 0};
        uint4* dst = (uint4*)(ypk + (size_t)p * 16);
        dst[0] = *(const uint4*)&t[0];
        dst[1] = *(const uint4*)&t[8];
    }
}

// ---------- main MFMA kernel: grid 64b x 16 strips(128 rows) ----------
__global__ __launch_bounds__(BLK, 4) void cf_mf(
    const unsigned short* __restrict__ qpk, const unsigned short* __restrict__ ypk,
    unsigned* __restrict__ minbuf)
{
    const int tid = threadIdx.x;
    const int bid = blockIdx.x;
    const int strip = bid & 15;
    const int b = bid >> 4;

    __shared__ unsigned short sA[128 * SROW];
    __shared__ unsigned short sB[128 * SROW];
    __shared__ float scolw[4][128];

    const uint4* qpk4 = (const uint4*)qpk;
    const uint4* ypk4 = (const uint4*)ypk;
    const int qbase = b * NPTS + strip * 128;
    const int ybase = b * NPTS;

    // stage A (128 rows x 32B) + zero k=16..31 of both tiles
    {
        const int row = tid >> 1, seg = tid & 1;
        *(uint4*)&sA[row * SROW + seg * 8] = qpk4[(size_t)(qbase + row) * 2 + seg];
        for (int idx2 = tid; idx2 < 2048; idx2 += 256) {
            const int r = idx2 >> 4, e = idx2 & 15;
            sA[r * SROW + 16 + e] = 0;
            sB[r * SROW + 16 + e] = 0;
        }
    }
    __syncthreads();

    const int l = tid & 63, w = tid >> 6;
    const int lm = l & 15, kb = l >> 4;

    // persistent A fragments: rows w*32+lm and +16, k-block kb
    const bf16x8 a0 = __builtin_bit_cast(bf16x8,
        *(const short8v*)&sA[(w * 32 + lm) * SROW + kb * 8]);
    const bf16x8 a1 = __builtin_bit_cast(bf16x8,
        *(const short8v*)&sA[(w * 32 + 16 + lm) * SROW + kb * 8]);

    float rm0[4], rm1[4];
#pragma unroll
    for (int r = 0; r < 4; ++r) { rm0[r] = INFINITY; rm1[r] = INFINITY; }

    unsigned* rowbuf = minbuf;
    unsigned* colbuf = minbuf + NB * NPTS;

    for (int cs = 0; cs < 16; ++cs) {
        __syncthreads();                       // prev sB/scolw consumed
        {
            const int row = tid >> 1, seg = tid & 1;
            *(uint4*)&sB[row * SROW + seg * 8] =
                ypk4[(size_t)(ybase + cs * 128 + row) * 2 + seg];
        }
        __syncthreads();                       // sB ready

        float cpart[8];
#pragma unroll
        for (int ct = 0; ct < 8; ++ct) {
            const bf16x8 bf = __builtin_bit_cast(bf16x8,
                *(const short8v*)&sB[(ct * 16 + lm) * SROW + kb * 8]);
            f32x4 z = {0.f, 0.f, 0.f, 0.f};
            f32x4 acc0 = __builtin_amdgcn_mfma_f32_16x16x32_bf16(a0, bf, z, 0, 0, 0);
            f32x4 acc1 = __builtin_amdgcn_mfma_f32_16x16x32_bf16(a1, bf, z, 0, 0, 0);
#pragma unroll
            for (int r = 0; r < 4; ++r) {
                rm0[r] = fminf(rm0[r], acc0[r]);
                rm1[r] = fminf(rm1[r], acc1[r]);
            }
            float cm = fminf(fminf(fminf(acc0[0], acc0[1]), fminf(acc0[2], acc0[3])),
                             fminf(fminf(acc1[0], acc1[1]), fminf(acc1[2], acc1[3])));
            cm = fminf(cm, __shfl_xor(cm, 16, 64));
            cm = fminf(cm, __shfl_xor(cm, 32, 64));
            cpart[ct] = cm;
        }
        if (l < 16) {
#pragma unroll
            for (int ct = 0; ct < 8; ++ct) scolw[w][ct * 16 + l] = cpart[ct];
        }
        __syncthreads();                       // scolw ready
        if (tid < 128) {
            const float m = fminf(fminf(scolw[0][tid], scolw[1][tid]),
                                  fminf(scolw[2][tid], scolw[3][tid]));
            atomicMin(&colbuf[b * NPTS + cs * 128 + tid],
                      __float_as_uint(fmaxf(m, 0.f)));
        }
    }

    // row mins: butterfly over the 16 col-lanes, then exclusive store
#pragma unroll
    for (int r = 0; r < 4; ++r) {
        float v0 = rm0[r], v1 = rm1[r];
        v0 = fminf(v0, __shfl_xor(v0, 1, 64));
        v0 = fminf(v0, __shfl_xor(v0, 2, 64));
        v0 = fminf(v0, __shfl_xor(v0, 4, 64));
        v0 = fminf(v0, __shfl_xor(v0, 8, 64));
        v1 = fminf(v1, __shfl_xor(v1, 1, 64));
        v1 = fminf(v1, __shfl_xor(v1, 2, 64));
        v1 = fminf(v1, __shfl_xor(v1, 4, 64));
        v1 = fminf(v1, __shfl_xor(v1, 8, 64));
        rm0[r] = v0; rm1[r] = v1;
    }
    if (lm == 0) {
        const int base = b * NPTS + strip * 128 + w * 32 + kb * 4;
#pragma unroll
        for (int r = 0; r < 4; ++r) {
            rowbuf[base + r]      = __float_as_uint(fmaxf(rm0[r], 0.f));
            rowbuf[base + 16 + r] = __float_as_uint(fmaxf(rm1[r], 0.f));
        }
    }
}

// ================= fallback (proven R6 path) if ws too small =================
#define FIT 128
#define FJT 128
#define PADI(j) ((j) + ((j) >> 4))

__global__ __launch_bounds__(256) void cf_init(unsigned* __restrict__ colbuf) {
    int i = blockIdx.x * 256 + threadIdx.x;
    colbuf[i] = 0x7F800000u;
}

__global__ __launch_bounds__(BLK, 4) void cf_tile_lds(
    const float* __restrict__ preds, const float* __restrict__ gts,
    const int* __restrict__ idx, unsigned* __restrict__ minbuf)
{
    const int tid = threadIdx.x;
    const int bid = blockIdx.x;
    const int it = bid & 15;
    const int b = bid >> 4;
    const int i0 = idx[2 * b];
    const int m1 = idx[2 * b + 1];
    const float* pbase = preds + i0 * PREDS_A + m1;
    const float* gbase = gts + i0 * GTS_A;

    __shared__ float4 sq[PADI(FIT - 1) + 2];
    __shared__ float4 sr[PADI(NPTS - 1) + 2];
    __shared__ float  scolw[4][FJT];

    if (tid < FIT) {
        const int i = it * FIT + tid;
        const float q0 = pbase[i * 8];
        const float q1 = pbase[i * 8 + PREDS_C];
        const float q2 = pbase[i * 8 + 2 * PREDS_C];
        const float rq = fmaf(q0, q0, fmaf(q1, q1, q2 * q2));
        sq[PADI(tid)] = make_float4(-2.f * q0, -2.f * q1, -2.f * q2, rq);
    }
#pragma unroll
    for (int k = 0; k < 8; ++k) {
        const int j = tid + BLK * k;
        const float r0 = gbase[j];
        const float r1 = gbase[j + GTS_C];
        const float r2 = gbase[j + 2 * GTS_C];
        const float rr = fmaf(r0, r0, fmaf(r1, r1, r2 * r2));
        sr[PADI(j)] = make_float4(r0, r1, r2, rr);
    }
    __syncthreads();

    const int ty = tid >> 4, tx = tid & 15;
    float nq0[8], nq1[8], nq2[8], rq[8], rmin[8];
#pragma unroll
    for (int u = 0; u < 8; ++u) {
        const float4 q = sq[PADI(ty * 8 + u)];
        nq0[u] = q.x; nq1[u] = q.y; nq2[u] = q.z; rq[u] = q.w;
        rmin[u] = INFINITY;
    }
    unsigned* rowbuf = minbuf;
    unsigned* colbuf = minbuf + NB * NPTS;

    for (int jt = 0; jt < NPTS / FJT; ++jt) {
        float4 r[8];
        const int rb = PADI(jt * FJT + tx * 8);
#pragma unroll
        for (int v = 0; v < 8; ++v) r[v] = sr[rb + v];
        float cmin[8];
#pragma unroll
        for (int v = 0; v < 8; ++v) cmin[v] = INFINITY;
#pragma unroll
        for (int v = 0; v < 8; v += 2) {
#pragma unroll
            for (int u = 0; u < 8; u += 2) {
                float s00 = fmaf(nq2[u], r[v].z, r[v].w);
                s00 = fmaf(nq1[u], r[v].y, s00);
                s00 = fmaf(nq0[u], r[v].x, s00);
                float s01 = fmaf(nq2[u], r[v + 1].z, r[v + 1].w);
                s01 = fmaf(nq1[u], r[v + 1].y, s01);
                s01 = fmaf(nq0[u], r[v + 1].x, s01);
                float s10 = fmaf(nq2[u + 1], r[v].z, r[v].w);
                s10 = fmaf(nq1[u + 1], r[v].y, s10);
                s10 = fmaf(nq0[u + 1], r[v].x, s10);
                float s11 = fmaf(nq2[u + 1], r[v + 1].z, r[v + 1].w);
                s11 = fmaf(nq1[u + 1], r[v + 1].y, s11);
                s11 = fmaf(nq0[u + 1], r[v + 1].x, s11);
                rmin[u]     = min3f(s00, s01, rmin[u]);
                rmin[u + 1] = min3f(s10, s11, rmin[u + 1]);
                const float d00 = s00 + rq[u];
                const float d10 = s10 + rq[u + 1];
                const float d01 = s01 + rq[u];
                const float d11 = s11 + rq[u + 1];
                cmin[v]     = min3f(d00, d10, cmin[v]);
                cmin[v + 1] = min3f(d01, d11, cmin[v + 1]);
            }
        }
#pragma unroll
        for (int v = 0; v < 8; ++v) {
            float c = cmin[v];
            c = fminf(c, __shfl_xor(c, 16, 64));
            c = fminf(c, __shfl_xor(c, 32, 64));
            cmin[v] = c;
        }
        if (((tid >> 4) & 3) == 0) {
            const int w = tid >> 6;
            *(float4*)&scolw[w][tx * 8]     = make_float4(cmin[0], cmin[1], cmin[2], cmin[3]);
            *(float4*)&scolw[w][tx * 8 + 4] = make_float4(cmin[4], cmin[5], cmin[6], cmin[7]);
        }
        __syncthreads();
        if (tid < FJT) {
            float m = fminf(min3f(scolw[0][tid], scolw[1][tid], scolw[2][tid]), scolw[3][tid]);
            m = fmaxf(m, 0.0f);
            atomicMin(&colbuf[b * NPTS + jt * FJT + tid], __float_as_uint(m));
        }
        __syncthreads();
    }
#pragma unroll
    for (int u = 0; u < 8; ++u) {
        float rm = rmin[u];
        rm = fminf(rm, __shfl_xor(rm, 1, 16));
        rm = fminf(rm, __shfl_xor(rm, 2, 16));
        rm = fminf(rm, __shfl_xor(rm, 4, 16));
        rm = fminf(rm, __shfl_xor(rm, 8, 16));
        rmin[u] = rm;
    }
    if (tx == 0) {
#pragma unroll
        for (int u = 0; u < 8; ++u) {
            const float d = fmaxf(rmin[u] + rq[u], 0.0f);
            rowbuf[b * NPTS + it * FIT + ty * 8 + u] = __float_as_uint(d);
        }
    }
}

// ================= final reductions =================
__global__ __launch_bounds__(256) void cf_reduce1(const unsigned* __restrict__ minbuf,
                                                  float* __restrict__ partial) {
    __shared__ float sm[4];
    const int base = blockIdx.x * 1024;
    float s = 0.0f;
    for (int k = threadIdx.x; k < 1024; k += 256)
        s += __uint_as_float(minbuf[base + k]);
#pragma unroll
    for (int off = 32; off > 0; off >>= 1)
        s += __shfl_down(s, off, 64);
    if ((threadIdx.x & 63) == 0) sm[threadIdx.x >> 6] = s;
    __syncthreads();
    if (threadIdx.x == 0)
        partial[blockIdx.x] = sm[0] + sm[1] + sm[2] + sm[3];
}

__global__ __launch_bounds__(256) void cf_reduce2(const float* __restrict__ partial,
                                                  float* __restrict__ out) {
    __shared__ float sm[4];
    float s = partial[threadIdx.x];
#pragma unroll
    for (int off = 32; off > 0; off >>= 1)
        s += __shfl_down(s, off, 64);
    if ((threadIdx.x & 63) == 0) sm[threadIdx.x >> 6] = s;
    __syncthreads();
    if (threadIdx.x == 0)
        out[0] = (sm[0] + sm[1] + sm[2] + sm[3]) * (1.0f / 64.0f);
}

extern "C" void kernel_launch(void* const* d_in, const int* in_sizes, int n_in,
                              void* d_out, int out_size, void* d_ws, size_t ws_size,
                              hipStream_t stream) {
    const float* preds = (const float*)d_in[0];
    const float* gts   = (const float*)d_in[1];
    const int*   idx   = (const int*)d_in[2];
    float* out = (float*)d_out;

    unsigned* minbuf = (unsigned*)d_ws;
    unsigned* colbuf = minbuf + NB * NPTS;
    float* partial   = (float*)((char*)d_ws + OFF_PARTIAL);

    if (ws_size >= (size_t)WS_REQ) {
        unsigned short* qpk = (unsigned short*)((char*)d_ws + OFF_QPK);
        unsigned short* ypk = (unsigned short*)((char*)d_ws + OFF_YPK);
        cf_pack<<<1536, 256, 0, stream>>>(preds, gts, idx, colbuf, qpk, ypk);
        cf_mf<<<NB * 16, BLK, 0, stream>>>(qpk, ypk, minbuf);
    } else {
        cf_init<<<(NB * NPTS) / 256, 256, 0, stream>>>(colbuf);
        cf_tile_lds<<<NB * (NPTS / FIT), BLK, 0, stream>>>(preds, gts, idx, minbuf);
    }
    cf_reduce1<<<NMIN / 1024, 256, 0, stream>>>(minbuf, partial);
    cf_reduce2<<<1, 256, 0, stream>>>(partial, out);
}

// Round 10
// 48.955 us; speedup vs baseline: 7.9275x; 1.1413x over previous
//
#include <hip/hip_runtime.h>

// ChamferLoss via 32x32x16 MFMA: preds (8,3,2048,8) f32, gts (8,3,2048) f32, idx (64,2).
// P[i][j] = rx_i + ry_j - 2 x_i.y_j inside one mfma_f32_32x32x16_bf16 per 32x32 tile
// via split-bf16 K-packing (13 of 16 K slots):
//   A_k = [ah0..2, ah0..2, al0..2, rxh, rxl, 1, 1, 0,0,0]   (a = -2x, hi/lo split)
//   B_k = [yh0..2, yl0..2, yh0..2, 1, 1, ryh, ryl, 0,0,0]
// Fragments are DIRECT GLOBAL LOADS (16B/lane, coalesced, L2-resident) -> no LDS
// staging, no main-loop barriers. rm[16] row-mins accumulate in registers; col-mins
// via one LDS atomicMin/tile into block-shared scolw[2048].

#define NPTS 2048
#define NB 64
#define BLK 256
#define NMIN (2 * NB * NPTS)

#define PREDS_A 49152
#define PREDS_C 16384
#define GTS_A 6144
#define GTS_C 2048

// ws layout
#define OFF_PARTIAL (NMIN * 4)
#define OFF_QPK     (OFF_PARTIAL + 4096)             // 64*2048*32B = 4 MB
#define OFF_YPK     (OFF_QPK + NB * NPTS * 32)
#define WS_REQ      (OFF_YPK + NB * NPTS * 32)       // ~9.4 MB

using bf16x8  = __attribute__((ext_vector_type(8))) __bf16;
using short8v = __attribute__((ext_vector_type(8))) short;
using f32x16  = __attribute__((ext_vector_type(16))) float;

static __device__ __forceinline__ unsigned short f2bf(float f) {
    unsigned u = __float_as_uint(f);
    u = u + 0x7FFFu + ((u >> 16) & 1u);      // RNE
    return (unsigned short)(u >> 16);
}
static __device__ __forceinline__ float bf2f(unsigned short h) {
    return __uint_as_float(((unsigned)h) << 16);
}
static __device__ __forceinline__ float min3f(float a, float b, float c) {
    return fminf(fminf(a, b), c);
}

// ---------- pack + init: 1536 blocks (layout identical to R9, verified exact) ----------
__global__ __launch_bounds__(256) void cf_pack(
    const float* __restrict__ preds, const float* __restrict__ gts,
    const int* __restrict__ idx, unsigned* __restrict__ colbuf,
    unsigned short* __restrict__ qpk, unsigned short* __restrict__ ypk)
{
    const int blk = blockIdx.x, tid = threadIdx.x;
    const unsigned short one = 0x3F80;
    if (blk < 512) {
        colbuf[blk * 256 + tid] = 0x7F800000u;
    } else if (blk < 1024) {
        const int p = (blk - 512) * 256 + tid;
        const int b = p >> 11, i = p & 2047;
        const int i0 = idx[2 * b], m1 = idx[2 * b + 1];
        const float* pb = preds + i0 * PREDS_A + m1 + i * 8;
        const float x0 = pb[0], x1 = pb[PREDS_C], x2 = pb[2 * PREDS_C];
        const float rx = fmaf(x0, x0, fmaf(x1, x1, x2 * x2));
        const float a0 = -2.f * x0, a1 = -2.f * x1, a2 = -2.f * x2;
        const unsigned short h0 = f2bf(a0), h1 = f2bf(a1), h2 = f2bf(a2);
        const unsigned short l0 = f2bf(a0 - bf2f(h0));
        const unsigned short l1 = f2bf(a1 - bf2f(h1));
        const unsigned short l2 = f2bf(a2 - bf2f(h2));
        const unsigned short rh = f2bf(rx), rl = f2bf(rx - bf2f(rh));
        alignas(16) unsigned short t[16] =
            {h0, h1, h2, h0, h1, h2, l0, l1, l2, rh, rl, one, one, 0, 0, 0};
        uint4* dst = (uint4*)(qpk + (size_t)p * 16);
        dst[0] = *(const uint4*)&t[0];
        dst[1] = *(const uint4*)&t[8];
    } else {
        const int p = (blk - 1024) * 256 + tid;
        const int b = p >> 11, j = p & 2047;
        const int i0 = idx[2 * b];
        const float* gb = gts + i0 * GTS_A + j;
        const float y0 = gb[0], y1 = gb[GTS_C], y2 = gb[2 * GTS_C];
        const float ry = fmaf(y0, y0, fmaf(y1, y1, y2 * y2));
        const unsigned short h0 = f2bf(y0), h1 = f2bf(y1), h2 = f2bf(y2);
        const unsigned short l0 = f2bf(y0 - bf2f(h0));
        const unsigned short l1 = f2bf(y1 - bf2f(h1));
        const unsigned short l2 = f2bf(y2 - bf2f(h2));
        const unsigned short rh = f2bf(ry), rl = f2bf(ry - bf2f(rh));
        alignas(16) unsigned short t[16] =
            {h0, h1, h2, l0, l1, l2, h0, h1, h2, one, one, rh, rl, 0, 0, 0};
        uint4* dst = (uint4*)(ypk + (size_t)p * 16);
        dst[0] = *(const uint4*)&t[0];
        dst[1] = *(const uint4*)&t[8];
    }
}

// ---------- main: 32x32x16 MFMA, global-fed fragments, barrier-free main loop ----------
// grid = 64 b x 16 strips(128 rows). Wave w owns rows strip*128 + w*32 .. +31.
__global__ __launch_bounds__(BLK) void cf_mf2(
    const unsigned short* __restrict__ qpk, const unsigned short* __restrict__ ypk,
    unsigned* __restrict__ minbuf)
{
    const int tid = threadIdx.x;
    const int bid = blockIdx.x;
    const int strip = bid & 15;
    const int b = bid >> 4;

    __shared__ unsigned scolw[NPTS];          // 8 KB: block-shared col mins (uint-float)
    for (int k = tid; k < NPTS; k += BLK) scolw[k] = 0x7F800000u;

    const int l = tid & 63, w = tid >> 6;
    const int lc = l & 31, lh = l >> 5;       // col-lane, k-half

    const short8v* qv = (const short8v*)qpk;  // 16B units; point = 2 units
    const short8v* yv = (const short8v*)ypk;

    // persistent A fragment: row = strip*128 + w*32 + lc, k-slots lh*8..+7
    const int arow = b * NPTS + strip * 128 + w * 32 + lc;
    const bf16x8 afrag = __builtin_bit_cast(bf16x8, qv[arow * 2 + lh]);

    float rm[16];
#pragma unroll
    for (int r = 0; r < 16; ++r) rm[r] = INFINITY;

    const f32x16 z = {0.f, 0.f, 0.f, 0.f, 0.f, 0.f, 0.f, 0.f,
                      0.f, 0.f, 0.f, 0.f, 0.f, 0.f, 0.f, 0.f};

    __syncthreads();                          // scolw init visible

    const int ybase = b * NPTS * 2 + lc * 2 + lh;
#pragma unroll 4
    for (int t = 0; t < 64; ++t) {
        const bf16x8 bfrag = __builtin_bit_cast(bf16x8, yv[ybase + t * 64]);
        f32x16 acc = __builtin_amdgcn_mfma_f32_32x32x16_bf16(afrag, bfrag, z, 0, 0, 0);
        // row mins: reg r -> row (r&3)+8*(r>>2)+4*lh (accumulate across tiles)
#pragma unroll
        for (int r = 0; r < 16; ++r) rm[r] = fminf(rm[r], acc[r]);
        // col min over this lane's 16 rows (lane l and l+32 merge via LDS atomic)
        const float c0 = min3f(acc[0], acc[1], acc[2]);
        const float c1 = min3f(acc[3], acc[4], acc[5]);
        const float c2 = min3f(acc[6], acc[7], acc[8]);
        const float c3 = min3f(acc[9], acc[10], acc[11]);
        const float c4 = min3f(acc[12], acc[13], acc[14]);
        float cm = min3f(c0, c1, acc[15]);
        cm = min3f(cm, c2, c3);
        cm = fminf(cm, c4);
        atomicMin(&scolw[t * 32 + lc], __float_as_uint(fmaxf(cm, 0.f)));
    }

    unsigned* rowbuf = minbuf;
    unsigned* colbuf = minbuf + NB * NPTS;

    // ---- row flush: butterfly over the 32 col-lanes of each half, exclusive store ----
#pragma unroll
    for (int r = 0; r < 16; ++r) {
        float v = rm[r];
        v = fminf(v, __shfl_xor(v, 1, 32));
        v = fminf(v, __shfl_xor(v, 2, 32));
        v = fminf(v, __shfl_xor(v, 4, 32));
        v = fminf(v, __shfl_xor(v, 8, 32));
        v = fminf(v, __shfl_xor(v, 16, 32));
        rm[r] = v;
    }
    if (lc == 0) {
        const int rbase = b * NPTS + strip * 128 + w * 32 + 4 * lh;
#pragma unroll
        for (int r = 0; r < 16; ++r)
            rowbuf[rbase + (r & 3) + 8 * (r >> 2)] = __float_as_uint(fmaxf(rm[r], 0.f));
    }

    // ---- col flush ----
    __syncthreads();
    for (int k = tid; k < NPTS; k += BLK)
        atomicMin(&colbuf[b * NPTS + k], scolw[k]);
}

// ================= fallback (proven R6 path) if ws too small =================
#define FIT 128
#define FJT 128
#define PADI(j) ((j) + ((j) >> 4))

__global__ __launch_bounds__(256) void cf_init(unsigned* __restrict__ colbuf) {
    int i = blockIdx.x * 256 + threadIdx.x;
    colbuf[i] = 0x7F800000u;
}

__global__ __launch_bounds__(BLK, 4) void cf_tile_lds(
    const float* __restrict__ preds, const float* __restrict__ gts,
    const int* __restrict__ idx, unsigned* __restrict__ minbuf)
{
    const int tid = threadIdx.x;
    const int bid = blockIdx.x;
    const int it = bid & 15;
    const int b = bid >> 4;
    const int i0 = idx[2 * b];
    const int m1 = idx[2 * b + 1];
    const float* pbase = preds + i0 * PREDS_A + m1;
    const float* gbase = gts + i0 * GTS_A;

    __shared__ float4 sq[PADI(FIT - 1) + 2];
    __shared__ float4 sr[PADI(NPTS - 1) + 2];
    __shared__ float  scolw[4][FJT];

    if (tid < FIT) {
        const int i = it * FIT + tid;
        const float q0 = pbase[i * 8];
        const float q1 = pbase[i * 8 + PREDS_C];
        const float q2 = pbase[i * 8 + 2 * PREDS_C];
        const float rq = fmaf(q0, q0, fmaf(q1, q1, q2 * q2));
        sq[PADI(tid)] = make_float4(-2.f * q0, -2.f * q1, -2.f * q2, rq);
    }
#pragma unroll
    for (int k = 0; k < 8; ++k) {
        const int j = tid + BLK * k;
        const float r0 = gbase[j];
        const float r1 = gbase[j + GTS_C];
        const float r2 = gbase[j + 2 * GTS_C];
        const float rr = fmaf(r0, r0, fmaf(r1, r1, r2 * r2));
        sr[PADI(j)] = make_float4(r0, r1, r2, rr);
    }
    __syncthreads();

    const int ty = tid >> 4, tx = tid & 15;
    float nq0[8], nq1[8], nq2[8], rq[8], rmin[8];
#pragma unroll
    for (int u = 0; u < 8; ++u) {
        const float4 q = sq[PADI(ty * 8 + u)];
        nq0[u] = q.x; nq1[u] = q.y; nq2[u] = q.z; rq[u] = q.w;
        rmin[u] = INFINITY;
    }
    unsigned* rowbuf = minbuf;
    unsigned* colbuf = minbuf + NB * NPTS;

    for (int jt = 0; jt < NPTS / FJT; ++jt) {
        float4 r[8];
        const int rb = PADI(jt * FJT + tx * 8);
#pragma unroll
        for (int v = 0; v < 8; ++v) r[v] = sr[rb + v];
        float cmin[8];
#pragma unroll
        for (int v = 0; v < 8; ++v) cmin[v] = INFINITY;
#pragma unroll
        for (int v = 0; v < 8; v += 2) {
#pragma unroll
            for (int u = 0; u < 8; u += 2) {
                float s00 = fmaf(nq2[u], r[v].z, r[v].w);
                s00 = fmaf(nq1[u], r[v].y, s00);
                s00 = fmaf(nq0[u], r[v].x, s00);
                float s01 = fmaf(nq2[u], r[v + 1].z, r[v + 1].w);
                s01 = fmaf(nq1[u], r[v + 1].y, s01);
                s01 = fmaf(nq0[u], r[v + 1].x, s01);
                float s10 = fmaf(nq2[u + 1], r[v].z, r[v].w);
                s10 = fmaf(nq1[u + 1], r[v].y, s10);
                s10 = fmaf(nq0[u + 1], r[v].x, s10);
                float s11 = fmaf(nq2[u + 1], r[v + 1].z, r[v + 1].w);
                s11 = fmaf(nq1[u + 1], r[v + 1].y, s11);
                s11 = fmaf(nq0[u + 1], r[v + 1].x, s11);
                rmin[u]     = min3f(s00, s01, rmin[u]);
                rmin[u + 1] = min3f(s10, s11, rmin[u + 1]);
                const float d00 = s00 + rq[u];
                const float d10 = s10 + rq[u + 1];
                const float d01 = s01 + rq[u];
                const float d11 = s11 + rq[u + 1];
                cmin[v]     = min3f(d00, d10, cmin[v]);
                cmin[v + 1] = min3f(d01, d11, cmin[v + 1]);
            }
        }
#pragma unroll
        for (int v = 0; v < 8; ++v) {
            float c = cmin[v];
            c = fminf(c, __shfl_xor(c, 16, 64));
            c = fminf(c, __shfl_xor(c, 32, 64));
            cmin[v] = c;
        }
        if (((tid >> 4) & 3) == 0) {
            const int w = tid >> 6;
            *(float4*)&scolw[w][tx * 8]     = make_float4(cmin[0], cmin[1], cmin[2], cmin[3]);
            *(float4*)&scolw[w][tx * 8 + 4] = make_float4(cmin[4], cmin[5], cmin[6], cmin[7]);
        }
        __syncthreads();
        if (tid < FJT) {
            float m = fminf(min3f(scolw[0][tid], scolw[1][tid], scolw[2][tid]), scolw[3][tid]);
            m = fmaxf(m, 0.0f);
            atomicMin(&colbuf[b * NPTS + jt * FJT + tid], __float_as_uint(m));
        }
        __syncthreads();
    }
#pragma unroll
    for (int u = 0; u < 8; ++u) {
        float rm = rmin[u];
        rm = fminf(rm, __shfl_xor(rm, 1, 16));
        rm = fminf(rm, __shfl_xor(rm, 2, 16));
        rm = fminf(rm, __shfl_xor(rm, 4, 16));
        rm = fminf(rm, __shfl_xor(rm, 8, 16));
        rmin[u] = rm;
    }
    if (tx == 0) {
#pragma unroll
        for (int u = 0; u < 8; ++u) {
            const float d = fmaxf(rmin[u] + rq[u], 0.0f);
            rowbuf[b * NPTS + it * FIT + ty * 8 + u] = __float_as_uint(d);
        }
    }
}

// ================= final reductions =================
__global__ __launch_bounds__(256) void cf_reduce1(const unsigned* __restrict__ minbuf,
                                                  float* __restrict__ partial) {
    __shared__ float sm[4];
    const int base = blockIdx.x * 1024;
    float s = 0.0f;
    for (int k = threadIdx.x; k < 1024; k += 256)
        s += __uint_as_float(minbuf[base + k]);
#pragma unroll
    for (int off = 32; off > 0; off >>= 1)
        s += __shfl_down(s, off, 64);
    if ((threadIdx.x & 63) == 0) sm[threadIdx.x >> 6] = s;
    __syncthreads();
    if (threadIdx.x == 0)
        partial[blockIdx.x] = sm[0] + sm[1] + sm[2] + sm[3];
}

__global__ __launch_bounds__(256) void cf_reduce2(const float* __restrict__ partial,
                                                  float* __restrict__ out) {
    __shared__ float sm[4];
    float s = partial[threadIdx.x];
#pragma unroll
    for (int off = 32; off > 0; off >>= 1)
        s += __shfl_down(s, off, 64);
    if ((threadIdx.x & 63) == 0) sm[threadIdx.x >> 6] = s;
    __syncthreads();
    if (threadIdx.x == 0)
        out[0] = (sm[0] + sm[1] + sm[2] + sm[3]) * (1.0f / 64.0f);
}

extern "C" void kernel_launch(void* const* d_in, const int* in_sizes, int n_in,
                              void* d_out, int out_size, void* d_ws, size_t ws_size,
                              hipStream_t stream) {
    const float* preds = (const float*)d_in[0];
    const float* gts   = (const float*)d_in[1];
    const int*   idx   = (const int*)d_in[2];
    float* out = (float*)d_out;

    unsigned* minbuf = (unsigned*)d_ws;
    unsigned* colbuf = minbuf + NB * NPTS;
    float* partial   = (float*)((char*)d_ws + OFF_PARTIAL);

    if (ws_size >= (size_t)WS_REQ) {
        unsigned short* qpk = (unsigned short*)((char*)d_ws + OFF_QPK);
        unsigned short* ypk = (unsigned short*)((char*)d_ws + OFF_YPK);
        cf_pack<<<1536, 256, 0, stream>>>(preds, gts, idx, colbuf, qpk, ypk);
        cf_mf2<<<NB * 16, BLK, 0, stream>>>(qpk, ypk, minbuf);
    } else {
        cf_init<<<(NB * NPTS) / 256, 256, 0, stream>>>(colbuf);
        cf_tile_lds<<<NB * (NPTS / FIT), BLK, 0, stream>>>(preds, gts, idx, minbuf);
    }
    cf_reduce1<<<NMIN / 1024, 256, 0, stream>>>(minbuf, partial);
    cf_reduce2<<<1, 256, 0, stream>>>(partial, out);
}

// Round 11
// 39.271 us; speedup vs baseline: 9.8825x; 1.2466x over previous
//
#include <hip/hip_runtime.h>

// ChamferLoss via 32x32x16 MFMA: preds (8,3,2048,8) f32, gts (8,3,2048) f32, idx (64,2).
// P[i][j] = rx_i + ry_j - 2 x_i.y_j inside one mfma_f32_32x32x16_bf16 per 32x32 tile
// via split-bf16 K-packing (13 of 16 K slots):
//   A_k = [ah0..2, ah0..2, al0..2, rxh, rxl, 1, 1, 0,0,0]   (a = -2x, hi/lo split)
//   B_k = [yh0..2, yl0..2, yh0..2, 1, 1, ryh, ryl, 0,0,0]
// R11: two-tile paired epilogue -> row mins 0.5 op/elem (min3 across tile pair),
// col tree 8 min3/tile; launch_bounds(256,4) pins 4 waves/SIMD. Barrier-free loop.

#define NPTS 2048
#define NB 64
#define BLK 256
#define NMIN (2 * NB * NPTS)

#define PREDS_A 49152
#define PREDS_C 16384
#define GTS_A 6144
#define GTS_C 2048

// ws layout
#define OFF_PARTIAL (NMIN * 4)
#define OFF_QPK     (OFF_PARTIAL + 4096)             // 64*2048*32B = 4 MB
#define OFF_YPK     (OFF_QPK + NB * NPTS * 32)
#define WS_REQ      (OFF_YPK + NB * NPTS * 32)       // ~9.4 MB

using bf16x8  = __attribute__((ext_vector_type(8))) __bf16;
using short8v = __attribute__((ext_vector_type(8))) short;
using f32x16  = __attribute__((ext_vector_type(16))) float;

static __device__ __forceinline__ unsigned short f2bf(float f) {
    unsigned u = __float_as_uint(f);
    u = u + 0x7FFFu + ((u >> 16) & 1u);      // RNE
    return (unsigned short)(u >> 16);
}
static __device__ __forceinline__ float bf2f(unsigned short h) {
    return __uint_as_float(((unsigned)h) << 16);
}
static __device__ __forceinline__ float min3f(float a, float b, float c) {
    return fminf(fminf(a, b), c);            // clang fuses to v_min3_f32
}
static __device__ __forceinline__ float ctree(f32x16 a) {
    const float c0 = min3f(a[0], a[1], a[2]);
    const float c1 = min3f(a[3], a[4], a[5]);
    const float c2 = min3f(a[6], a[7], a[8]);
    const float c3 = min3f(a[9], a[10], a[11]);
    const float c4 = min3f(a[12], a[13], a[14]);
    const float d0 = min3f(c0, c1, a[15]);
    const float d1 = min3f(c2, c3, c4);
    return fminf(d0, d1);                    // 8 ops for 16 elems
}

// ---------- pack + init: 1536 blocks (layout identical to R9/R10, verified) ----------
__global__ __launch_bounds__(256) void cf_pack(
    const float* __restrict__ preds, const float* __restrict__ gts,
    const int* __restrict__ idx, unsigned* __restrict__ colbuf,
    unsigned short* __restrict__ qpk, unsigned short* __restrict__ ypk)
{
    const int blk = blockIdx.x, tid = threadIdx.x;
    const unsigned short one = 0x3F80;
    if (blk < 512) {
        colbuf[blk * 256 + tid] = 0x7F800000u;
    } else if (blk < 1024) {
        const int p = (blk - 512) * 256 + tid;
        const int b = p >> 11, i = p & 2047;
        const int i0 = idx[2 * b], m1 = idx[2 * b + 1];
        const float* pb = preds + i0 * PREDS_A + m1 + i * 8;
        const float x0 = pb[0], x1 = pb[PREDS_C], x2 = pb[2 * PREDS_C];
        const float rx = fmaf(x0, x0, fmaf(x1, x1, x2 * x2));
        const float a0 = -2.f * x0, a1 = -2.f * x1, a2 = -2.f * x2;
        const unsigned short h0 = f2bf(a0), h1 = f2bf(a1), h2 = f2bf(a2);
        const unsigned short l0 = f2bf(a0 - bf2f(h0));
        const unsigned short l1 = f2bf(a1 - bf2f(h1));
        const unsigned short l2 = f2bf(a2 - bf2f(h2));
        const unsigned short rh = f2bf(rx), rl = f2bf(rx - bf2f(rh));
        alignas(16) unsigned short t[16] =
            {h0, h1, h2, h0, h1, h2, l0, l1, l2, rh, rl, one, one, 0, 0, 0};
        uint4* dst = (uint4*)(qpk + (size_t)p * 16);
        dst[0] = *(const uint4*)&t[0];
        dst[1] = *(const uint4*)&t[8];
    } else {
        const int p = (blk - 1024) * 256 + tid;
        const int b = p >> 11, j = p & 2047;
        const int i0 = idx[2 * b];
        const float* gb = gts + i0 * GTS_A + j;
        const float y0 = gb[0], y1 = gb[GTS_C], y2 = gb[2 * GTS_C];
        const float ry = fmaf(y0, y0, fmaf(y1, y1, y2 * y2));
        const unsigned short h0 = f2bf(y0), h1 = f2bf(y1), h2 = f2bf(y2);
        const unsigned short l0 = f2bf(y0 - bf2f(h0));
        const unsigned short l1 = f2bf(y1 - bf2f(h1));
        const unsigned short l2 = f2bf(y2 - bf2f(h2));
        const unsigned short rh = f2bf(ry), rl = f2bf(ry - bf2f(rh));
        alignas(16) unsigned short t[16] =
            {h0, h1, h2, l0, l1, l2, h0, h1, h2, one, one, rh, rl, 0, 0, 0};
        uint4* dst = (uint4*)(ypk + (size_t)p * 16);
        dst[0] = *(const uint4*)&t[0];
        dst[1] = *(const uint4*)&t[8];
    }
}

// ---------- main: paired 32x32x16 MFMA tiles, barrier-free, 4 waves/SIMD ----------
// grid = 64 b x 16 strips(128 rows). Wave w owns rows strip*128 + w*32 .. +31.
__global__ __launch_bounds__(BLK, 4) void cf_mf3(
    const unsigned short* __restrict__ qpk, const unsigned short* __restrict__ ypk,
    unsigned* __restrict__ minbuf)
{
    const int tid = threadIdx.x;
    const int bid = blockIdx.x;
    const int strip = bid & 15;
    const int b = bid >> 4;

    __shared__ unsigned scolw[NPTS];          // 8 KB block-shared col mins
    for (int k = tid; k < NPTS; k += BLK) scolw[k] = 0x7F800000u;

    const int l = tid & 63, w = tid >> 6;
    const int lc = l & 31, lh = l >> 5;       // col-lane, k-half

    const short8v* qv = (const short8v*)qpk;  // 16B units; point = 2 units
    const short8v* yv = (const short8v*)ypk;

    const int arow = b * NPTS + strip * 128 + w * 32 + lc;
    const bf16x8 afrag = __builtin_bit_cast(bf16x8, qv[arow * 2 + lh]);

    float rm[16];
#pragma unroll
    for (int r = 0; r < 16; ++r) rm[r] = INFINITY;

    const f32x16 z = {0.f, 0.f, 0.f, 0.f, 0.f, 0.f, 0.f, 0.f,
                      0.f, 0.f, 0.f, 0.f, 0.f, 0.f, 0.f, 0.f};

    __syncthreads();                          // scolw init visible

    const int ybase = b * NPTS * 2 + lc * 2 + lh;
#pragma unroll 2
    for (int s = 0; s < 32; ++s) {
        const bf16x8 bfA = __builtin_bit_cast(bf16x8, yv[ybase + (2 * s) * 64]);
        const bf16x8 bfB = __builtin_bit_cast(bf16x8, yv[ybase + (2 * s + 1) * 64]);
        f32x16 accA = __builtin_amdgcn_mfma_f32_32x32x16_bf16(afrag, bfA, z, 0, 0, 0);
        f32x16 accB = __builtin_amdgcn_mfma_f32_32x32x16_bf16(afrag, bfB, z, 0, 0, 0);
        // rows: pair the two tiles -> 16 min3 for 2048 elems (0.5 op/elem)
#pragma unroll
        for (int r = 0; r < 16; ++r) rm[r] = min3f(accA[r], accB[r], rm[r]);
        // cols: 8-op min3 tree per tile; lanes l and l+32 merge via LDS atomic
        const float cmA = ctree(accA);
        const float cmB = ctree(accB);
        atomicMin(&scolw[(2 * s) * 32 + lc], __float_as_uint(fmaxf(cmA, 0.f)));
        atomicMin(&scolw[(2 * s + 1) * 32 + lc], __float_as_uint(fmaxf(cmB, 0.f)));
    }

    unsigned* rowbuf = minbuf;
    unsigned* colbuf = minbuf + NB * NPTS;

    // ---- row flush: butterfly over 32 col-lanes, exclusive store ----
#pragma unroll
    for (int r = 0; r < 16; ++r) {
        float v = rm[r];
        v = fminf(v, __shfl_xor(v, 1, 32));
        v = fminf(v, __shfl_xor(v, 2, 32));
        v = fminf(v, __shfl_xor(v, 4, 32));
        v = fminf(v, __shfl_xor(v, 8, 32));
        v = fminf(v, __shfl_xor(v, 16, 32));
        rm[r] = v;
    }
    if (lc == 0) {
        const int rbase = b * NPTS + strip * 128 + w * 32 + 4 * lh;
#pragma unroll
        for (int r = 0; r < 16; ++r)
            rowbuf[rbase + (r & 3) + 8 * (r >> 2)] = __float_as_uint(fmaxf(rm[r], 0.f));
    }

    // ---- col flush ----
    __syncthreads();
    for (int k = tid; k < NPTS; k += BLK)
        atomicMin(&colbuf[b * NPTS + k], scolw[k]);
}

// ================= fallback (proven R6 path) if ws too small =================
#define FIT 128
#define FJT 128
#define PADI(j) ((j) + ((j) >> 4))

__global__ __launch_bounds__(256) void cf_init(unsigned* __restrict__ colbuf) {
    int i = blockIdx.x * 256 + threadIdx.x;
    colbuf[i] = 0x7F800000u;
}

__global__ __launch_bounds__(BLK, 4) void cf_tile_lds(
    const float* __restrict__ preds, const float* __restrict__ gts,
    const int* __restrict__ idx, unsigned* __restrict__ minbuf)
{
    const int tid = threadIdx.x;
    const int bid = blockIdx.x;
    const int it = bid & 15;
    const int b = bid >> 4;
    const int i0 = idx[2 * b];
    const int m1 = idx[2 * b + 1];
    const float* pbase = preds + i0 * PREDS_A + m1;
    const float* gbase = gts + i0 * GTS_A;

    __shared__ float4 sq[PADI(FIT - 1) + 2];
    __shared__ float4 sr[PADI(NPTS - 1) + 2];
    __shared__ float  scolw[4][FJT];

    if (tid < FIT) {
        const int i = it * FIT + tid;
        const float q0 = pbase[i * 8];
        const float q1 = pbase[i * 8 + PREDS_C];
        const float q2 = pbase[i * 8 + 2 * PREDS_C];
        const float rq = fmaf(q0, q0, fmaf(q1, q1, q2 * q2));
        sq[PADI(tid)] = make_float4(-2.f * q0, -2.f * q1, -2.f * q2, rq);
    }
#pragma unroll
    for (int k = 0; k < 8; ++k) {
        const int j = tid + BLK * k;
        const float r0 = gbase[j];
        const float r1 = gbase[j + GTS_C];
        const float r2 = gbase[j + 2 * GTS_C];
        const float rr = fmaf(r0, r0, fmaf(r1, r1, r2 * r2));
        sr[PADI(j)] = make_float4(r0, r1, r2, rr);
    }
    __syncthreads();

    const int ty = tid >> 4, tx = tid & 15;
    float nq0[8], nq1[8], nq2[8], rq[8], rmin[8];
#pragma unroll
    for (int u = 0; u < 8; ++u) {
        const float4 q = sq[PADI(ty * 8 + u)];
        nq0[u] = q.x; nq1[u] = q.y; nq2[u] = q.z; rq[u] = q.w;
        rmin[u] = INFINITY;
    }
    unsigned* rowbuf = minbuf;
    unsigned* colbuf = minbuf + NB * NPTS;

    for (int jt = 0; jt < NPTS / FJT; ++jt) {
        float4 r[8];
        const int rb = PADI(jt * FJT + tx * 8);
#pragma unroll
        for (int v = 0; v < 8; ++v) r[v] = sr[rb + v];
        float cmin[8];
#pragma unroll
        for (int v = 0; v < 8; ++v) cmin[v] = INFINITY;
#pragma unroll
        for (int v = 0; v < 8; v += 2) {
#pragma unroll
            for (int u = 0; u < 8; u += 2) {
                float s00 = fmaf(nq2[u], r[v].z, r[v].w);
                s00 = fmaf(nq1[u], r[v].y, s00);
                s00 = fmaf(nq0[u], r[v].x, s00);
                float s01 = fmaf(nq2[u], r[v + 1].z, r[v + 1].w);
                s01 = fmaf(nq1[u], r[v + 1].y, s01);
                s01 = fmaf(nq0[u], r[v + 1].x, s01);
                float s10 = fmaf(nq2[u + 1], r[v].z, r[v].w);
                s10 = fmaf(nq1[u + 1], r[v].y, s10);
                s10 = fmaf(nq0[u + 1], r[v].x, s10);
                float s11 = fmaf(nq2[u + 1], r[v + 1].z, r[v + 1].w);
                s11 = fmaf(nq1[u + 1], r[v + 1].y, s11);
                s11 = fmaf(nq0[u + 1], r[v + 1].x, s11);
                rmin[u]     = min3f(s00, s01, rmin[u]);
                rmin[u + 1] = min3f(s10, s11, rmin[u + 1]);
                const float d00 = s00 + rq[u];
                const float d10 = s10 + rq[u + 1];
                const float d01 = s01 + rq[u];
                const float d11 = s11 + rq[u + 1];
                cmin[v]     = min3f(d00, d10, cmin[v]);
                cmin[v + 1] = min3f(d01, d11, cmin[v + 1]);
            }
        }
#pragma unroll
        for (int v = 0; v < 8; ++v) {
            float c = cmin[v];
            c = fminf(c, __shfl_xor(c, 16, 64));
            c = fminf(c, __shfl_xor(c, 32, 64));
            cmin[v] = c;
        }
        if (((tid >> 4) & 3) == 0) {
            const int w = tid >> 6;
            *(float4*)&scolw[w][tx * 8]     = make_float4(cmin[0], cmin[1], cmin[2], cmin[3]);
            *(float4*)&scolw[w][tx * 8 + 4] = make_float4(cmin[4], cmin[5], cmin[6], cmin[7]);
        }
        __syncthreads();
        if (tid < FJT) {
            float m = fminf(min3f(scolw[0][tid], scolw[1][tid], scolw[2][tid]), scolw[3][tid]);
            m = fmaxf(m, 0.0f);
            atomicMin(&colbuf[b * NPTS + jt * FJT + tid], __float_as_uint(m));
        }
        __syncthreads();
    }
#pragma unroll
    for (int u = 0; u < 8; ++u) {
        float rm = rmin[u];
        rm = fminf(rm, __shfl_xor(rm, 1, 16));
        rm = fminf(rm, __shfl_xor(rm, 2, 16));
        rm = fminf(rm, __shfl_xor(rm, 4, 16));
        rm = fminf(rm, __shfl_xor(rm, 8, 16));
        rmin[u] = rm;
    }
    if (tx == 0) {
#pragma unroll
        for (int u = 0; u < 8; ++u) {
            const float d = fmaxf(rmin[u] + rq[u], 0.0f);
            rowbuf[b * NPTS + it * FIT + ty * 8 + u] = __float_as_uint(d);
        }
    }
}

// ================= final reductions =================
__global__ __launch_bounds__(256) void cf_reduce1(const unsigned* __restrict__ minbuf,
                                                  float* __restrict__ partial) {
    __shared__ float sm[4];
    const int base = blockIdx.x * 1024;
    float s = 0.0f;
    for (int k = threadIdx.x; k < 1024; k += 256)
        s += __uint_as_float(minbuf[base + k]);
#pragma unroll
    for (int off = 32; off > 0; off >>= 1)
        s += __shfl_down(s, off, 64);
    if ((threadIdx.x & 63) == 0) sm[threadIdx.x >> 6] = s;
    __syncthreads();
    if (threadIdx.x == 0)
        partial[blockIdx.x] = sm[0] + sm[1] + sm[2] + sm[3];
}

__global__ __launch_bounds__(256) void cf_reduce2(const float* __restrict__ partial,
                                                  float* __restrict__ out) {
    __shared__ float sm[4];
    float s = partial[threadIdx.x];
#pragma unroll
    for (int off = 32; off > 0; off >>= 1)
        s += __shfl_down(s, off, 64);
    if ((threadIdx.x & 63) == 0) sm[threadIdx.x >> 6] = s;
    __syncthreads();
    if (threadIdx.x == 0)
        out[0] = (sm[0] + sm[1] + sm[2] + sm[3]) * (1.0f / 64.0f);
}

extern "C" void kernel_launch(void* const* d_in, const int* in_sizes, int n_in,
                              void* d_out, int out_size, void* d_ws, size_t ws_size,
                              hipStream_t stream) {
    const float* preds = (const float*)d_in[0];
    const float* gts   = (const float*)d_in[1];
    const int*   idx   = (const int*)d_in[2];
    float* out = (float*)d_out;

    unsigned* minbuf = (unsigned*)d_ws;
    unsigned* colbuf = minbuf + NB * NPTS;
    float* partial   = (float*)((char*)d_ws + OFF_PARTIAL);

    if (ws_size >= (size_t)WS_REQ) {
        unsigned short* qpk = (unsigned short*)((char*)d_ws + OFF_QPK);
        unsigned short* ypk = (unsigned short*)((char*)d_ws + OFF_YPK);
        cf_pack<<<1536, 256, 0, stream>>>(preds, gts, idx, colbuf, qpk, ypk);
        cf_mf3<<<NB * 16, BLK, 0, stream>>>(qpk, ypk, minbuf);
    } else {
        cf_init<<<(NB * NPTS) / 256, 256, 0, stream>>>(colbuf);
        cf_tile_lds<<<NB * (NPTS / FIT), BLK, 0, stream>>>(preds, gts, idx, minbuf);
    }
    cf_reduce1<<<NMIN / 1024, 256, 0, stream>>>(minbuf, partial);
    cf_reduce2<<<1, 256, 0, stream>>>(partial, out);
}